// Round 5
// baseline (698.571 us; speedup 1.0000x reference)
//
#include <hip/hip_runtime.h>
#include <hip/hip_bf16.h>
#include <type_traits>
#include <math.h>

// ---------------------------------------------------------------------------
// Attention: out = softmax_causal((x Wq^T + bq)(x Wk^T + bk)^T / sqrt(D)) (x Wv^T + bv) Wp^T + bp
// B=4, S=2048, D=2048, fp32 in/out, bf16 MFMA compute.
//
// R4: wave-tile switched from 4x4 of 16x16x32 to 2x2 of 32x32x16 MFMA
// (same FLOP, half the MFMA instructions, ~17% fewer MFMA-pipe cycles per
// m06/m119 cycle constants). XOR-swizzled BK=64 LDS layout kept (0 bank
// conflicts, verified R3). attn*V row-strip permutation balances the 16:1
// causal K-length imbalance across scheduling rounds.
//
// Workspace layout (256 MB):
//   [0,32)MB    xb    bf16 x              [8192,2048]
//   [32,56)MB   wqkv  bf16 [Wq;Wk;Wv]     [6144,2048]
//   [56,64)MB   wpb   bf16 Wp             [2048,2048]
//   [64,96)MB   qb    bf16 Q              (later reused as attn P)
//   [96,128)MB  kb    bf16 K              (later reused as ctx)
//   [160,192)MB vtb   bf16 V^T per batch  [B][D][S]
//   [192,256)MB sc    fp32 scores         [B,S,S]
// ---------------------------------------------------------------------------

typedef __bf16 bf16x8_t __attribute__((ext_vector_type(8)));
typedef float f32x16_t __attribute__((ext_vector_type(16)));
typedef unsigned short u16x8_t __attribute__((ext_vector_type(8)));

#define BM 128
#define BN 128
#define BK 64

__device__ inline unsigned short f2bf(float f) {
  unsigned int u = __builtin_bit_cast(unsigned int, f);
  unsigned int r = u + 0x7fffu + ((u >> 16) & 1u);
  return (unsigned short)(r >> 16);
}

// async global->LDS, 16B per lane; lds dest = wave-uniform base + lane*16
__device__ inline void gl2lds16(const unsigned short* g, unsigned short* l) {
  __builtin_amdgcn_global_load_lds(
      (const __attribute__((address_space(1))) unsigned int*)g,
      (__attribute__((address_space(3))) unsigned int*)l, 16, 0, 0);
}

// ---------------- cast fp32 -> bf16 (x input) ------------------------------
__global__ __launch_bounds__(256) void cast_f32_bf16(
    const float* __restrict__ in, unsigned short* __restrict__ out, long n4) {
  long i = blockIdx.x * 256L + threadIdx.x;
  if (i >= n4) return;
  float4 f = ((const float4*)in)[i];
  ushort4 u;
  u.x = f2bf(f.x); u.y = f2bf(f.y); u.z = f2bf(f.z); u.w = f2bf(f.w);
  ((ushort4*)out)[i] = u;
}

// ---------------- fused 4-weight cast: blockIdx.y selects matrix -----------
__global__ __launch_bounds__(256) void cast_w4(
    const float* __restrict__ w0, const float* __restrict__ w1,
    const float* __restrict__ w2, const float* __restrict__ w3,
    unsigned short* __restrict__ o0, unsigned short* __restrict__ o1,
    unsigned short* __restrict__ o2, unsigned short* __restrict__ o3,
    long n4) {
  long i = blockIdx.x * 256L + threadIdx.x;
  if (i >= n4) return;
  const float* in; unsigned short* out;
  switch (blockIdx.y) {
    case 0: in = w0; out = o0; break;
    case 1: in = w1; out = o1; break;
    case 2: in = w2; out = o2; break;
    default: in = w3; out = o3; break;
  }
  float4 f = ((const float4*)in)[i];
  ushort4 u;
  u.x = f2bf(f.x); u.y = f2bf(f.y); u.z = f2bf(f.z); u.w = f2bf(f.w);
  ((ushort4*)out)[i] = u;
}

// ===================== shared GEMM K-loop (macro body) =====================
// Tile [128][64] bf16 = 16 KB = 16 chunks of 1 KB (8 rows x 8 slots of 16B).
// Staging: wave w stages chunks 4w..4w+3 of both tiles; lane l -> row l>>3,
// physical slot l&7, fetching swizzled global column ((l&7)^(l>>3))*8.
// Fragments (32x32x16): lane l -> row/col = l&31, k-group = l>>5; logical
// 16B slot for k-step j is 2j+kgrp, physical slot XORed by (row&7).
#define GEMM_PROLOGUE()                                                        \
  const int tid = threadIdx.x;                                                 \
  const int lane = tid & 63;                                                   \
  const int wave = tid >> 6;                                                   \
  const int wm = (wave >> 1) * 64;                                             \
  const int wn = (wave & 1) * 64;                                              \
  __shared__ unsigned short smem[2 * BM * BK]; /* 32 KB */                     \
  unsigned short* As = smem;                                                   \
  unsigned short* Bs = smem + BM * BK;                                         \
  const int lr = lane >> 3;                                                    \
  const int swcol = ((lane & 7) ^ lr) * 8;                                     \
  const int cbase = wave * 4;                                                  \
  f32x16_t acc[2][2] = {};                                                     \
  const int frow = lane & 31;                                                  \
  const int kgrp = lane >> 5;                                                  \
  int fo[4];                                                                   \
  _Pragma("unroll")                                                            \
  for (int j = 0; j < 4; j++) fo[j] = ((j * 2 + kgrp) ^ (frow & 7)) * 8;

#define GEMM_KLOOP(Ab, Bb, K, Keff)                                            \
  for (int k0 = 0; k0 < (Keff); k0 += BK) {                                    \
    __syncthreads();                                                           \
    _Pragma("unroll")                                                          \
    for (int i = 0; i < 4; i++) {                                              \
      const int c = cbase + i;                                                 \
      gl2lds16((Ab) + (size_t)(c * 8 + lr) * (K) + k0 + swcol, As + c * 512);  \
      gl2lds16((Bb) + (size_t)(c * 8 + lr) * (K) + k0 + swcol, Bs + c * 512);  \
    }                                                                          \
    __syncthreads();                                                           \
    _Pragma("unroll")                                                          \
    for (int j = 0; j < 4; j++) {                                              \
      bf16x8_t af0 = __builtin_bit_cast(                                       \
          bf16x8_t, *(const u16x8_t*)&As[(wm + frow) * BK + fo[j]]);           \
      bf16x8_t af1 = __builtin_bit_cast(                                       \
          bf16x8_t, *(const u16x8_t*)&As[(wm + 32 + frow) * BK + fo[j]]);      \
      bf16x8_t bv0 = __builtin_bit_cast(                                       \
          bf16x8_t, *(const u16x8_t*)&Bs[(wn + frow) * BK + fo[j]]);           \
      bf16x8_t bv1 = __builtin_bit_cast(                                       \
          bf16x8_t, *(const u16x8_t*)&Bs[(wn + 32 + frow) * BK + fo[j]]);      \
      acc[0][0] = __builtin_amdgcn_mfma_f32_32x32x16_bf16(af0, bv0, acc[0][0], 0, 0, 0); \
      acc[0][1] = __builtin_amdgcn_mfma_f32_32x32x16_bf16(af0, bv1, acc[0][1], 0, 0, 0); \
      acc[1][0] = __builtin_amdgcn_mfma_f32_32x32x16_bf16(af1, bv0, acc[1][0], 0, 0, 0); \
      acc[1][1] = __builtin_amdgcn_mfma_f32_32x32x16_bf16(af1, bv1, acc[1][1], 0, 0, 0); \
    }                                                                          \
  }

// ---------------- generic NT GEMM (modes 0/1/2) ----------------------------
// MODE 0: plain. MODE 1: causal block skip. MODE 2: causal K-limit with
// balanced row-strip permutation (grid.y must be 16).
template <int MODE, typename OutT>
__global__ __launch_bounds__(256) void gemm_nt(
    const unsigned short* __restrict__ A, const unsigned short* __restrict__ B,
    OutT* __restrict__ C, const float* __restrict__ bias, float alpha,
    int M, int N, int K, size_t sA, size_t sB, size_t sC) {
  int by = blockIdx.y;
  if (MODE == 2) by = (by & 1) ? (15 - (by >> 1)) : (by >> 1);  // balance Keff
  const int bm = by * BM;
  const int bn = blockIdx.x * BN;
  if (MODE == 1 && bn >= bm + BM) return;
  int Keff = K;
  if (MODE == 2) { int kl = bm + BM; Keff = kl < K ? kl : K; }

  A += (size_t)blockIdx.z * sA;
  B += (size_t)blockIdx.z * sB;
  C += (size_t)blockIdx.z * sC;

  GEMM_PROLOGUE();
  const unsigned short* Ab = A + (size_t)bm * K;
  const unsigned short* Bb = B + (size_t)bn * K;
  GEMM_KLOOP(Ab, Bb, K, Keff);

  // C/D layout (32x32): col = lane&31, row = (reg&3) + 8*(reg>>2) + 4*(lane>>5)
  const int cc = lane & 31;
  const int rb = 4 * (lane >> 5);
#pragma unroll
  for (int ni = 0; ni < 2; ni++) {
    const int col = bn + wn + ni * 32 + cc;
    const float bs = bias ? bias[col] : 0.f;
#pragma unroll
    for (int mi = 0; mi < 2; mi++) {
      const int rowb = bm + wm + mi * 32 + rb;
#pragma unroll
      for (int g = 0; g < 4; g++)
#pragma unroll
        for (int r = 0; r < 4; r++) {
          float v = acc[mi][ni][g * 4 + r] * alpha + bs;
          const int row = rowb + g * 8 + r;
          if constexpr (std::is_same_v<OutT, float>)
            C[(size_t)row * N + col] = v;
          else
            C[(size_t)row * N + col] = f2bf(v);
        }
    }
  }
}

// ---------------- fused QKV GEMM: N = 3*D, triple-destination epilogue -----
// B matrix = [Wq;Wk;Wv] stacked rows [3D, D]. col<D -> Q, col<2D -> K,
// else V stored TRANSPOSED per batch: vtb[b][d][s] (contiguous ushort4 in s).
__global__ __launch_bounds__(256) void gemm_qkv(
    const unsigned short* __restrict__ A, const unsigned short* __restrict__ Bw,
    unsigned short* __restrict__ Q, unsigned short* __restrict__ Kd,
    unsigned short* __restrict__ Vt,
    const float* __restrict__ bq, const float* __restrict__ bk,
    const float* __restrict__ bv, int K, int D, int S) {
  const int bm = blockIdx.y * BM;
  const int bn = blockIdx.x * BN;

  GEMM_PROLOGUE();
  const unsigned short* Ab = A + (size_t)bm * K;
  const unsigned short* Bb = Bw + (size_t)bn * K;
  GEMM_KLOOP(Ab, Bb, K, K);

  const int cc = lane & 31;
  const int rb = 4 * (lane >> 5);
#pragma unroll
  for (int ni = 0; ni < 2; ni++) {
    const int col = bn + wn + ni * 32 + cc;       // [0, 3D)
    const int sel = col >> 11;                    // 0:Q 1:K 2:V (block-uniform)
    const int idx = col & (D - 1);
    const float bs = (sel == 0 ? bq : sel == 1 ? bk : bv)[idx];
#pragma unroll
    for (int mi = 0; mi < 2; mi++) {
      const int rowb = bm + wm + mi * 32 + rb;
      if (sel < 2) {
        unsigned short* dst = sel == 0 ? Q : Kd;
#pragma unroll
        for (int g = 0; g < 4; g++)
#pragma unroll
          for (int r = 0; r < 4; r++)
            dst[(size_t)(rowb + g * 8 + r) * D + idx] =
                f2bf(acc[mi][ni][g * 4 + r] + bs);
      } else {
#pragma unroll
        for (int g = 0; g < 4; g++) {
          const int row = rowb + g * 8;           // 4 consecutive rows
          const int b = row >> 11;                // S=2048, block-uniform
          const int s = row & (S - 1);            // multiple of 4
          ushort4 pack;
          pack.x = f2bf(acc[mi][ni][g * 4 + 0] + bs);
          pack.y = f2bf(acc[mi][ni][g * 4 + 1] + bs);
          pack.z = f2bf(acc[mi][ni][g * 4 + 2] + bs);
          pack.w = f2bf(acc[mi][ni][g * 4 + 3] + bs);
          *(ushort4*)&Vt[(size_t)b * D * S + (size_t)idx * S + s] = pack;
        }
      }
    }
  }
}

// ---------------- causal softmax: fp32 scores row -> bf16 attn row ----------
__global__ __launch_bounds__(256) void softmax_causal(
    const float* __restrict__ Sc, unsigned short* __restrict__ P, int n) {
  const int row = blockIdx.x;
  const int q = row & (n - 1);
  const float* srow = Sc + (size_t)row * n;
  unsigned short* prow = P + (size_t)row * n;
  const int tid = threadIdx.x, lane = tid & 63, wid = tid >> 6;
  __shared__ float red[4];

  float m = -3.0e38f;
  for (int j = tid; j <= q; j += 256) m = fmaxf(m, srow[j]);
#pragma unroll
  for (int o = 32; o; o >>= 1) m = fmaxf(m, __shfl_down(m, o, 64));
  if (lane == 0) red[wid] = m;
  __syncthreads();
  m = fmaxf(fmaxf(red[0], red[1]), fmaxf(red[2], red[3]));
  __syncthreads();

  float s = 0.f;
  for (int j = tid; j <= q; j += 256) s += __expf(srow[j] - m);
#pragma unroll
  for (int o = 32; o; o >>= 1) s += __shfl_down(s, o, 64);
  if (lane == 0) red[wid] = s;
  __syncthreads();
  s = red[0] + red[1] + red[2] + red[3];
  const float inv = 1.f / s;

  for (int j = tid; j < n; j += 256) {
    float v = (j <= q) ? __expf(srow[j] - m) * inv : 0.f;
    prow[j] = f2bf(v);
  }
}

// ---------------------------------------------------------------------------
extern "C" void kernel_launch(void* const* d_in, const int* in_sizes, int n_in,
                              void* d_out, int out_size, void* d_ws, size_t ws_size,
                              hipStream_t stream) {
  const int B = 4, S = 2048, D = 2048;
  const int M = B * S;  // 8192

  const float* x  = (const float*)d_in[0];
  // d_in[1] = mask: guaranteed causal tril, hardcoded in kernels
  const float* Wq = (const float*)d_in[2];
  const float* bq = (const float*)d_in[3];
  const float* Wk = (const float*)d_in[4];
  const float* bk = (const float*)d_in[5];
  const float* Wv = (const float*)d_in[6];
  const float* bv = (const float*)d_in[7];
  const float* Wp = (const float*)d_in[8];
  const float* bp = (const float*)d_in[9];
  float* out = (float*)d_out;

  char* ws = (char*)d_ws;
  const size_t MB = 1ull << 20;
  unsigned short* xb   = (unsigned short*)(ws + 0);
  unsigned short* wqkv = (unsigned short*)(ws + 32 * MB);  // [6144,2048]
  unsigned short* wpb  = (unsigned short*)(ws + 56 * MB);
  unsigned short* qb   = (unsigned short*)(ws + 64 * MB);
  unsigned short* kb   = (unsigned short*)(ws + 96 * MB);
  unsigned short* vtb  = (unsigned short*)(ws + 160 * MB);
  float*          sc   = (float*)(ws + 192 * MB);
  unsigned short* pb   = qb;  // attn reuses Q (dead after scores GEMM)
  unsigned short* cb   = kb;  // ctx reuses K (dead after scores GEMM)

  const long nx = (long)M * D;
  const long nw = (long)D * D;

  // 1) casts: x, then all 4 weights in one launch (into stacked layout)
  cast_f32_bf16<<<dim3((unsigned)((nx / 4 + 255) / 256)), 256, 0, stream>>>(x, xb, nx / 4);
  cast_w4<<<dim3((unsigned)((nw / 4 + 255) / 256), 4), 256, 0, stream>>>(
      Wq, Wk, Wv, Wp,
      wqkv, wqkv + (size_t)D * D, wqkv + 2 * (size_t)D * D, wpb, nw / 4);

  const dim3 blk(256);

  // 2) fused QKV projection (N=6144, 3072 blocks); V written transposed
  gemm_qkv<<<dim3(3 * D / BN, M / BM), blk, 0, stream>>>(
      xb, wqkv, qb, kb, vtb, bq, bk, bv, D, D, S);

  // 3) scores = Q K^T * inv_std (fp32 out, causal block skip)
  const float inv_std = 1.f / sqrtf((float)D);
  gemm_nt<1, float><<<dim3(S / BN, S / BM, B), blk, 0, stream>>>(
      qb, kb, sc, nullptr, inv_std, S, S, D, (size_t)S * D, (size_t)S * D, (size_t)S * S);

  // 4) causal softmax -> bf16 attn
  softmax_causal<<<dim3(B * S), blk, 0, stream>>>(sc, pb, S);

  // 5) ctx = attn @ V  (via V^T, NT form; K-range capped at diagonal, balanced)
  gemm_nt<2, unsigned short><<<dim3(D / BN, S / BM, B), blk, 0, stream>>>(
      pb, vtb, cb, nullptr, 1.f, S, D, S, (size_t)S * S, (size_t)D * S, (size_t)S * D);

  // 6) out = ctx Wp^T + bp (fp32 out)
  gemm_nt<0, float><<<dim3(D / BN, M / BM), blk, 0, stream>>>(
      cb, wpb, out, bp, 1.f, M, D, D, 0, 0, 0);
}